// Round 1
// baseline (367.112 us; speedup 1.0000x reference)
//
#include <hip/hip_runtime.h>
#include <math.h>

#define BS   32
#define NA   8400
#define NMAX 64
#define NC   80
#define TOPKN 13

// out layout (floats)
#define OFF_LABELS 0
#define OFF_BBOX   (BS*NA)                 // 268800
#define OFF_SCORES (BS*NA + BS*NA*4)       // 1344000
#define OFF_FG     (BS*NA*5 + BS*NA*NC)    // 22848000
#define OFF_TGT    (BS*NA*6 + BS*NA*NC)    // 23116800

__device__ __forceinline__ float ciou_f(float g0, float g1, float g2, float g3,
                                        float p0, float p1, float p2, float p3) {
    const float eps = 1e-7f;
    float w1 = g2 - g0, h1 = g3 - g1;
    float w2 = p2 - p0, h2 = p3 - p1;
    float iw = fmaxf(fminf(g2, p2) - fmaxf(g0, p0), 0.f);
    float ih = fmaxf(fminf(g3, p3) - fmaxf(g1, p1), 0.f);
    float inter = iw * ih;
    float uni = w1 * h1 + w2 * h2 - inter + eps;
    float iou = inter / uni;
    float cw = fmaxf(g2, p2) - fminf(g0, p0);
    float ch = fmaxf(g3, p3) - fminf(g1, p1);
    float c2 = cw * cw + ch * ch + eps;
    float dx = p0 + p2 - g0 - g2;
    float dy = p1 + p3 - g1 - g3;
    float rho2 = (dx * dx + dy * dy) * 0.25f;
    const float four_over_pi2 = 4.0f / 9.869604401089358f;
    float dv = atanf(w2 / h2) - atanf(w1 / h1);
    float v = four_over_pi2 * dv * dv;
    float a = v / (v - iou + (1.0f + eps));
    return iou - (rho2 / c2 + v * a);
}

__device__ __forceinline__ float pow6f(float x) { float x2 = x * x; return x2 * x2 * x2; }

// Phase A: per (b,j): build full align row in LDS, exact top-13 (value desc, index asc),
// register claims for entries passing mask_in_gts (mask_gt already gated at block level).
__global__ __launch_bounds__(256) void kernA(const float* __restrict__ pd_scores,
                                             const float* __restrict__ pd_bboxes,
                                             const float* __restrict__ anc,
                                             const int*   __restrict__ gt_labels,
                                             const float* __restrict__ gt_bboxes,
                                             const float* __restrict__ mask_gt,
                                             int* __restrict__ claim_count,
                                             int* __restrict__ claimed_j) {
    const int j = blockIdx.x, b = blockIdx.y;
    const int tid = threadIdx.x;

    __shared__ float s_align[NA];
    __shared__ float s_rv[256];
    __shared__ int   s_ri[256];
    __shared__ int   s_sel[TOPKN];

    const float mg = mask_gt[b * NMAX + j];
    if (mg == 0.f) return;  // block-uniform: no candidates possible from this gt

    const int   label = gt_labels[b * NMAX + j];
    const float g0 = gt_bboxes[(b * NMAX + j) * 4 + 0];
    const float g1 = gt_bboxes[(b * NMAX + j) * 4 + 1];
    const float g2 = gt_bboxes[(b * NMAX + j) * 4 + 2];
    const float g3 = gt_bboxes[(b * NMAX + j) * 4 + 3];
    const float* pb = pd_bboxes + (size_t)b * NA * 4;
    const float* ps = pd_scores + (size_t)b * NA * NC;

    for (int a = tid; a < NA; a += 256) {
        float ax = anc[a * 2 + 0], ay = anc[a * 2 + 1];
        float d = fminf(fminf(ax - g0, ay - g1), fminf(g2 - ax, g3 - ay));
        float al = 0.f;
        if (d > 1e-9f) {
            float p0 = pb[a * 4 + 0], p1 = pb[a * 4 + 1];
            float p2 = pb[a * 4 + 2], p3 = pb[a * 4 + 3];
            float cv = fmaxf(ciou_f(g0, g1, g2, g3, p0, p1, p2, p3), 0.f);
            if (cv > 0.f) al = ps[a * NC + label] * pow6f(cv);
        }
        s_align[a] = al;
    }
    __syncthreads();

    // 13 sequential exact argmaxes with (value desc, index asc) tie-break.
    for (int k = 0; k < TOPKN; k++) {
        float bv = -2.f; int bi = NA;
        for (int a = tid; a < NA; a += 256) {
            float v = s_align[a];
            if (v > bv || (v == bv && a < bi)) { bv = v; bi = a; }
        }
        s_rv[tid] = bv; s_ri[tid] = bi;
        __syncthreads();
        for (int off = 128; off >= 1; off >>= 1) {
            if (tid < off) {
                float v2 = s_rv[tid + off]; int i2 = s_ri[tid + off];
                if (v2 > s_rv[tid] || (v2 == s_rv[tid] && i2 < s_ri[tid])) {
                    s_rv[tid] = v2; s_ri[tid] = i2;
                }
            }
            __syncthreads();
        }
        if (tid == 0) {
            int sel = s_ri[0];
            s_sel[k] = sel;
            s_align[sel] = -1.f;  // never re-selected (all real values >= 0)
        }
        __syncthreads();
    }

    if (tid < TOPKN) {
        int a = s_sel[tid];
        float ax = anc[a * 2 + 0], ay = anc[a * 2 + 1];
        float d = fminf(fminf(ax - g0, ay - g1), fminf(g2 - ax, g3 - ay));
        if (d > 1e-9f) {  // mask_in_gts; mask_gt already true
            atomicAdd(&claim_count[b * NA + a], 1);
            claimed_j[b * NA + a] = j;  // races only when count>1, where it's unused
        }
    }
}

// Phase B: resolve assignment per anchor; compute assigned align; per-gt max via atomicMax.
__global__ __launch_bounds__(256) void kernB(const float* __restrict__ pd_scores,
                                             const float* __restrict__ pd_bboxes,
                                             const float* __restrict__ anc,
                                             const int*   __restrict__ gt_labels,
                                             const float* __restrict__ gt_bboxes,
                                             const float* __restrict__ mask_gt,
                                             const int* __restrict__ claim_count,
                                             const int* __restrict__ claimed_j,
                                             int* __restrict__ assigned_j,
                                             float* __restrict__ assigned_align,
                                             unsigned int* __restrict__ gt_max) {
    int idx = blockIdx.x * blockDim.x + threadIdx.x;
    if (idx >= BS * NA) return;
    int b = idx / NA, a = idx - b * NA;

    int cnt = claim_count[idx];
    if (cnt == 0) { assigned_j[idx] = -1; assigned_align[idx] = 0.f; return; }

    float ax = anc[a * 2 + 0], ay = anc[a * 2 + 1];
    float p0 = pd_bboxes[((size_t)b * NA + a) * 4 + 0];
    float p1 = pd_bboxes[((size_t)b * NA + a) * 4 + 1];
    float p2 = pd_bboxes[((size_t)b * NA + a) * 4 + 2];
    float p3 = pd_bboxes[((size_t)b * NA + a) * 4 + 3];

    int ja;
    if (cnt == 1) {
        ja = claimed_j[idx];
    } else {
        // argmax_j overlaps (first max), overlaps = m ? clip0(ciou) : 0
        float best = -1.f; ja = 0;
        for (int j = 0; j < NMAX; j++) {
            float mgj = mask_gt[b * NMAX + j];
            float ov = 0.f;
            if (mgj != 0.f) {
                float g0 = gt_bboxes[(b * NMAX + j) * 4 + 0];
                float g1 = gt_bboxes[(b * NMAX + j) * 4 + 1];
                float g2 = gt_bboxes[(b * NMAX + j) * 4 + 2];
                float g3 = gt_bboxes[(b * NMAX + j) * 4 + 3];
                float d = fminf(fminf(ax - g0, ay - g1), fminf(g2 - ax, g3 - ay));
                if (d > 1e-9f)
                    ov = fmaxf(ciou_f(g0, g1, g2, g3, p0, p1, p2, p3), 0.f);
            }
            if (ov > best) { best = ov; ja = j; }
        }
    }

    // align_metric at (ja, a) with mask applied
    float val = 0.f;
    float mgj = mask_gt[b * NMAX + ja];
    if (mgj != 0.f) {
        float g0 = gt_bboxes[(b * NMAX + ja) * 4 + 0];
        float g1 = gt_bboxes[(b * NMAX + ja) * 4 + 1];
        float g2 = gt_bboxes[(b * NMAX + ja) * 4 + 2];
        float g3 = gt_bboxes[(b * NMAX + ja) * 4 + 3];
        float d = fminf(fminf(ax - g0, ay - g1), fminf(g2 - ax, g3 - ay));
        if (d > 1e-9f) {
            float cv = fmaxf(ciou_f(g0, g1, g2, g3, p0, p1, p2, p3), 0.f);
            if (cv > 0.f) {
                int lab = gt_labels[b * NMAX + ja];
                val = pd_scores[((size_t)b * NA + a) * NC + lab] * pow6f(cv);
            }
        }
    }
    assigned_j[idx] = ja;
    assigned_align[idx] = val;
    atomicMax(&gt_max[b * NMAX + ja], __float_as_uint(val));  // val >= 0: uint order == float order
}

// Phase C1: scalar outputs (labels, bboxes, fg, gt_idx)
__global__ __launch_bounds__(256) void kernC1(const int* __restrict__ gt_labels,
                                              const float* __restrict__ gt_bboxes,
                                              const int* __restrict__ assigned_j,
                                              float* __restrict__ out) {
    int idx = blockIdx.x * blockDim.x + threadIdx.x;
    if (idx >= BS * NA) return;
    int b = idx / NA;
    int ja = assigned_j[idx];
    int fg = (ja >= 0);
    int tgt = fg ? ja : 0;

    out[OFF_LABELS + idx] = (float)gt_labels[b * NMAX + tgt];
    const float4 bb = *(const float4*)&gt_bboxes[(b * NMAX + tgt) * 4];
    *(float4*)&out[OFF_BBOX + idx * 4] = bb;
    out[OFF_FG + idx]  = fg ? 1.f : 0.f;
    out[OFF_TGT + idx] = (float)tgt;
}

// Phase C2: target_scores (bs, na, nc)
__global__ __launch_bounds__(256) void kernC2(const int* __restrict__ gt_labels,
                                              const int* __restrict__ assigned_j,
                                              const float* __restrict__ assigned_align,
                                              const unsigned int* __restrict__ gt_max,
                                              float* __restrict__ out) {
    int sidx = blockIdx.x * blockDim.x + threadIdx.x;
    if (sidx >= BS * NA * NC) return;
    int idx = sidx / NC;
    int c = sidx - idx * NC;
    int ja = assigned_j[idx];
    float outv = 0.f;
    if (ja >= 0) {
        int b = idx / NA;
        int lab = gt_labels[b * NMAX + ja];
        if (c == lab) {
            float v = assigned_align[idx];
            float dyn = 0.4f * __uint_as_float(gt_max[b * NMAX + ja]);
            outv = v / (dyn + 1e-9f);
        }
    }
    out[OFF_SCORES + sidx] = outv;
}

extern "C" void kernel_launch(void* const* d_in, const int* in_sizes, int n_in,
                              void* d_out, int out_size, void* d_ws, size_t ws_size,
                              hipStream_t stream) {
    const float* pd_scores = (const float*)d_in[0];
    const float* pd_bboxes = (const float*)d_in[1];
    const float* anc       = (const float*)d_in[2];
    const int*   gt_labels = (const int*)d_in[3];
    const float* gt_bboxes = (const float*)d_in[4];
    const float* mask_gt   = (const float*)d_in[5];
    float* out = (float*)d_out;

    char* ws = (char*)d_ws;
    int*          claim_count    = (int*)ws;                                    // BS*NA ints
    unsigned int* gt_max         = (unsigned int*)(ws + (size_t)BS * NA * 4);   // BS*NMAX
    int*          claimed_j      = (int*)(ws + (size_t)BS * NA * 4 + BS * NMAX * 4);
    int*          assigned_j     = (int*)(ws + (size_t)BS * NA * 8 + BS * NMAX * 4);
    float*        assigned_align = (float*)(ws + (size_t)BS * NA * 12 + BS * NMAX * 4);

    // zero claim_count + gt_max (ws is poisoned 0xAA before each call)
    hipMemsetAsync(d_ws, 0, (size_t)BS * NA * 4 + (size_t)BS * NMAX * 4, stream);

    kernA<<<dim3(NMAX, BS), 256, 0, stream>>>(pd_scores, pd_bboxes, anc, gt_labels,
                                              gt_bboxes, mask_gt, claim_count, claimed_j);
    int nanch = BS * NA;
    kernB<<<(nanch + 255) / 256, 256, 0, stream>>>(pd_scores, pd_bboxes, anc, gt_labels,
                                                   gt_bboxes, mask_gt, claim_count, claimed_j,
                                                   assigned_j, assigned_align, gt_max);
    kernC1<<<(nanch + 255) / 256, 256, 0, stream>>>(gt_labels, gt_bboxes, assigned_j, out);
    int nsc = BS * NA * NC;
    kernC2<<<(nsc + 255) / 256, 256, 0, stream>>>(gt_labels, assigned_j, assigned_align,
                                                  gt_max, out);
}

// Round 2
// 245.127 us; speedup vs baseline: 1.4976x; 1.4976x over previous
//
#include <hip/hip_runtime.h>
#include <math.h>

#define BS   32
#define NA   8400
#define NMAX 64
#define NC   80
#define TOPKN 13
#define CAP  1536   // candidate capacity; physical max in-gt anchors ~< 500 (gt wh <= 128)

// out layout (floats)
#define OFF_LABELS 0
#define OFF_BBOX   (BS*NA)                 // 268800
#define OFF_SCORES (BS*NA + BS*NA*4)       // 1344000
#define OFF_FG     (BS*NA*5 + BS*NA*NC)    // 22848000
#define OFF_TGT    (BS*NA*6 + BS*NA*NC)    // 23116800

__device__ __forceinline__ float ciou_f(float g0, float g1, float g2, float g3,
                                        float p0, float p1, float p2, float p3) {
    const float eps = 1e-7f;
    float w1 = g2 - g0, h1 = g3 - g1;
    float w2 = p2 - p0, h2 = p3 - p1;
    float iw = fmaxf(fminf(g2, p2) - fmaxf(g0, p0), 0.f);
    float ih = fmaxf(fminf(g3, p3) - fmaxf(g1, p1), 0.f);
    float inter = iw * ih;
    float uni = w1 * h1 + w2 * h2 - inter + eps;
    float iou = inter / uni;
    float cw = fmaxf(g2, p2) - fminf(g0, p0);
    float ch = fmaxf(g3, p3) - fminf(g1, p1);
    float c2 = cw * cw + ch * ch + eps;
    float dx = p0 + p2 - g0 - g2;
    float dy = p1 + p3 - g1 - g3;
    float rho2 = (dx * dx + dy * dy) * 0.25f;
    const float four_over_pi2 = 4.0f / 9.869604401089358f;
    float dv = atanf(w2 / h2) - atanf(w1 / h1);
    float v = four_over_pi2 * dv * dv;
    float a = v / (v - iou + (1.0f + eps));
    return iou - (rho2 / c2 + v * a);
}

__device__ __forceinline__ float pow6f(float x) { float x2 = x * x; return x2 * x2 * x2; }

// align value for anchor a vs gt (g0..g3,label); also returns d (in-gt margin).
// Must be the ONE code path so recomputation is bit-identical.
__device__ __forceinline__ float align_at(int a, float g0, float g1, float g2, float g3,
                                          int label, const float* __restrict__ anc,
                                          const float* __restrict__ pb,
                                          const float* __restrict__ ps, float& d_out) {
    float ax = anc[a * 2 + 0], ay = anc[a * 2 + 1];
    float d = fminf(fminf(ax - g0, ay - g1), fminf(g2 - ax, g3 - ay));
    d_out = d;
    float al = 0.f;
    if (d > 1e-9f) {
        float p0 = pb[a * 4 + 0], p1 = pb[a * 4 + 1];
        float p2 = pb[a * 4 + 2], p3 = pb[a * 4 + 3];
        float cv = fmaxf(ciou_f(g0, g1, g2, g3, p0, p1, p2, p3), 0.f);
        if (cv > 0.f) al = ps[a * NC + label] * pow6f(cv);
    }
    return al;
}

// Phase A: per (b,j): compact positives into LDS list, exact top-13 by
// (value desc, index asc); zero-tail picks = lowest-index zeros (claim iff in-gt).
__global__ __launch_bounds__(256) void kernA(const float* __restrict__ pd_scores,
                                             const float* __restrict__ pd_bboxes,
                                             const float* __restrict__ anc,
                                             const int*   __restrict__ gt_labels,
                                             const float* __restrict__ gt_bboxes,
                                             const float* __restrict__ mask_gt,
                                             int* __restrict__ claim_count,
                                             int* __restrict__ claimed_j) {
    const int j = blockIdx.x, b = blockIdx.y;
    const int tid = threadIdx.x;
    const int wid = tid >> 6, lane = tid & 63;

    __shared__ float s_cv[CAP];
    __shared__ int   s_ci[CAP];
    __shared__ int   s_cnt;
    __shared__ float s_rv[4];
    __shared__ int   s_ri[4];
    __shared__ int   s_sel[TOPKN];

    const float mg = mask_gt[b * NMAX + j];
    if (mg == 0.f) return;  // block-uniform exit

    if (tid == 0) s_cnt = 0;
    __syncthreads();

    const int   label = gt_labels[b * NMAX + j];
    const float g0 = gt_bboxes[(b * NMAX + j) * 4 + 0];
    const float g1 = gt_bboxes[(b * NMAX + j) * 4 + 1];
    const float g2 = gt_bboxes[(b * NMAX + j) * 4 + 2];
    const float g3 = gt_bboxes[(b * NMAX + j) * 4 + 3];
    const float* pb = pd_bboxes + (size_t)b * NA * 4;
    const float* ps = pd_scores + (size_t)b * NA * NC;

    for (int a = tid; a < NA; a += 256) {
        float d;
        float al = align_at(a, g0, g1, g2, g3, label, anc, pb, ps, d);
        if (al > 0.f) {
            int slot = atomicAdd(&s_cnt, 1);
            if (slot < CAP) { s_cv[slot] = al; s_ci[slot] = a; }
        }
    }
    __syncthreads();

    const int P = min(s_cnt, CAP);
    const int K1 = min(P, TOPKN);

    // K1 argmax passes over the candidate list, (value desc, index asc).
    for (int k = 0; k < K1; k++) {
        float bv = -2.f; int bi = NA;
        for (int t = tid; t < P; t += 256) {
            float v = s_cv[t];
            int   i = s_ci[t];
            if (v > bv || (v == bv && i < bi)) { bv = v; bi = i; }
        }
        // wave butterfly reduce (carries candidate-slot too via re-scan trick:
        // we reduce on (v, anchor-idx) then mark by matching slot below)
        #pragma unroll
        for (int off = 32; off >= 1; off >>= 1) {
            float v2 = __shfl_down(bv, off, 64);
            int   i2 = __shfl_down(bi, off, 64);
            if (v2 > bv || (v2 == bv && i2 < bi)) { bv = v2; bi = i2; }
        }
        if (lane == 0) { s_rv[wid] = bv; s_ri[wid] = bi; }
        __syncthreads();
        if (tid == 0) {
            float fv = s_rv[0]; int fi = s_ri[0];
            #pragma unroll
            for (int w = 1; w < 4; w++) {
                float v2 = s_rv[w]; int i2 = s_ri[w];
                if (v2 > fv || (v2 == fv && i2 < fi)) { fv = v2; fi = i2; }
            }
            s_sel[k] = fi;
            // mark selected candidate so it can't win again
            for (int t = 0; t < P; t++) {
                if (s_ci[t] == fi) { s_cv[t] = -1.f; break; }
            }
        }
        __syncthreads();
    }

    // claims for selected positives (al>0 implies in-gt: no recheck needed)
    if (tid < K1) {
        int a = s_sel[tid];
        atomicAdd(&claim_count[b * NA + a], 1);
        claimed_j[b * NA + a] = j;  // races only when count>1, where it's unused
    }

    // zero-tail: top_k fills remaining picks with lowest-index zero entries;
    // each claims only if in-gt (mask_in_gts). Sequential scan from a=0.
    if (tid == 0 && K1 < TOPKN) {
        int need = TOPKN - K1;
        for (int a = 0; a < NA && need > 0; a++) {
            float d;
            float al = align_at(a, g0, g1, g2, g3, label, anc, pb, ps, d);
            if (al == 0.f) {
                if (d > 1e-9f) {
                    atomicAdd(&claim_count[b * NA + a], 1);
                    claimed_j[b * NA + a] = j;
                }
                need--;
            }
        }
    }
}

// Phase B: resolve assignment per anchor; compute assigned align; per-gt max via atomicMax.
__global__ __launch_bounds__(256) void kernB(const float* __restrict__ pd_scores,
                                             const float* __restrict__ pd_bboxes,
                                             const float* __restrict__ anc,
                                             const int*   __restrict__ gt_labels,
                                             const float* __restrict__ gt_bboxes,
                                             const float* __restrict__ mask_gt,
                                             const int* __restrict__ claim_count,
                                             const int* __restrict__ claimed_j,
                                             int* __restrict__ assigned_j,
                                             float* __restrict__ assigned_align,
                                             unsigned int* __restrict__ gt_max) {
    int idx = blockIdx.x * blockDim.x + threadIdx.x;
    if (idx >= BS * NA) return;
    int b = idx / NA, a = idx - b * NA;

    int cnt = claim_count[idx];
    if (cnt == 0) { assigned_j[idx] = -1; assigned_align[idx] = 0.f; return; }

    float ax = anc[a * 2 + 0], ay = anc[a * 2 + 1];
    float p0 = pd_bboxes[((size_t)b * NA + a) * 4 + 0];
    float p1 = pd_bboxes[((size_t)b * NA + a) * 4 + 1];
    float p2 = pd_bboxes[((size_t)b * NA + a) * 4 + 2];
    float p3 = pd_bboxes[((size_t)b * NA + a) * 4 + 3];

    int ja;
    if (cnt == 1) {
        ja = claimed_j[idx];
    } else {
        // argmax_j overlaps (first max), overlaps = m ? clip0(ciou) : 0
        float best = -1.f; ja = 0;
        for (int j = 0; j < NMAX; j++) {
            float mgj = mask_gt[b * NMAX + j];
            float ov = 0.f;
            if (mgj != 0.f) {
                float g0 = gt_bboxes[(b * NMAX + j) * 4 + 0];
                float g1 = gt_bboxes[(b * NMAX + j) * 4 + 1];
                float g2 = gt_bboxes[(b * NMAX + j) * 4 + 2];
                float g3 = gt_bboxes[(b * NMAX + j) * 4 + 3];
                float d = fminf(fminf(ax - g0, ay - g1), fminf(g2 - ax, g3 - ay));
                if (d > 1e-9f)
                    ov = fmaxf(ciou_f(g0, g1, g2, g3, p0, p1, p2, p3), 0.f);
            }
            if (ov > best) { best = ov; ja = j; }
        }
    }

    // align_metric at (ja, a) with mask applied
    float val = 0.f;
    float mgj = mask_gt[b * NMAX + ja];
    if (mgj != 0.f) {
        float g0 = gt_bboxes[(b * NMAX + ja) * 4 + 0];
        float g1 = gt_bboxes[(b * NMAX + ja) * 4 + 1];
        float g2 = gt_bboxes[(b * NMAX + ja) * 4 + 2];
        float g3 = gt_bboxes[(b * NMAX + ja) * 4 + 3];
        float d = fminf(fminf(ax - g0, ay - g1), fminf(g2 - ax, g3 - ay));
        if (d > 1e-9f) {
            float cv = fmaxf(ciou_f(g0, g1, g2, g3, p0, p1, p2, p3), 0.f);
            if (cv > 0.f) {
                int lab = gt_labels[b * NMAX + ja];
                val = pd_scores[((size_t)b * NA + a) * NC + lab] * pow6f(cv);
            }
        }
    }
    assigned_j[idx] = ja;
    assigned_align[idx] = val;
    atomicMax(&gt_max[b * NMAX + ja], __float_as_uint(val));  // val >= 0: uint order == float order
}

// Phase C1: scalar outputs (labels, bboxes, fg, gt_idx)
__global__ __launch_bounds__(256) void kernC1(const int* __restrict__ gt_labels,
                                              const float* __restrict__ gt_bboxes,
                                              const int* __restrict__ assigned_j,
                                              float* __restrict__ out) {
    int idx = blockIdx.x * blockDim.x + threadIdx.x;
    if (idx >= BS * NA) return;
    int b = idx / NA;
    int ja = assigned_j[idx];
    int fg = (ja >= 0);
    int tgt = fg ? ja : 0;

    out[OFF_LABELS + idx] = (float)gt_labels[b * NMAX + tgt];
    const float4 bb = *(const float4*)&gt_bboxes[(b * NMAX + tgt) * 4];
    *(float4*)&out[OFF_BBOX + idx * 4] = bb;
    out[OFF_FG + idx]  = fg ? 1.f : 0.f;
    out[OFF_TGT + idx] = (float)tgt;
}

// Phase C2: target_scores (bs, na, nc)
__global__ __launch_bounds__(256) void kernC2(const int* __restrict__ gt_labels,
                                              const int* __restrict__ assigned_j,
                                              const float* __restrict__ assigned_align,
                                              const unsigned int* __restrict__ gt_max,
                                              float* __restrict__ out) {
    int sidx = blockIdx.x * blockDim.x + threadIdx.x;
    if (sidx >= BS * NA * NC) return;
    int idx = sidx / NC;
    int c = sidx - idx * NC;
    int ja = assigned_j[idx];
    float outv = 0.f;
    if (ja >= 0) {
        int b = idx / NA;
        int lab = gt_labels[b * NMAX + ja];
        if (c == lab) {
            float v = assigned_align[idx];
            float dyn = 0.4f * __uint_as_float(gt_max[b * NMAX + ja]);
            outv = v / (dyn + 1e-9f);
        }
    }
    out[OFF_SCORES + sidx] = outv;
}

extern "C" void kernel_launch(void* const* d_in, const int* in_sizes, int n_in,
                              void* d_out, int out_size, void* d_ws, size_t ws_size,
                              hipStream_t stream) {
    const float* pd_scores = (const float*)d_in[0];
    const float* pd_bboxes = (const float*)d_in[1];
    const float* anc       = (const float*)d_in[2];
    const int*   gt_labels = (const int*)d_in[3];
    const float* gt_bboxes = (const float*)d_in[4];
    const float* mask_gt   = (const float*)d_in[5];
    float* out = (float*)d_out;

    char* ws = (char*)d_ws;
    int*          claim_count    = (int*)ws;                                    // BS*NA ints
    unsigned int* gt_max         = (unsigned int*)(ws + (size_t)BS * NA * 4);   // BS*NMAX
    int*          claimed_j      = (int*)(ws + (size_t)BS * NA * 4 + BS * NMAX * 4);
    int*          assigned_j     = (int*)(ws + (size_t)BS * NA * 8 + BS * NMAX * 4);
    float*        assigned_align = (float*)(ws + (size_t)BS * NA * 12 + BS * NMAX * 4);

    // zero claim_count + gt_max (ws is poisoned 0xAA before each call)
    hipMemsetAsync(d_ws, 0, (size_t)BS * NA * 4 + (size_t)BS * NMAX * 4, stream);

    kernA<<<dim3(NMAX, BS), 256, 0, stream>>>(pd_scores, pd_bboxes, anc, gt_labels,
                                              gt_bboxes, mask_gt, claim_count, claimed_j);
    int nanch = BS * NA;
    kernB<<<(nanch + 255) / 256, 256, 0, stream>>>(pd_scores, pd_bboxes, anc, gt_labels,
                                                   gt_bboxes, mask_gt, claim_count, claimed_j,
                                                   assigned_j, assigned_align, gt_max);
    kernC1<<<(nanch + 255) / 256, 256, 0, stream>>>(gt_labels, gt_bboxes, assigned_j, out);
    int nsc = BS * NA * NC;
    kernC2<<<(nsc + 255) / 256, 256, 0, stream>>>(gt_labels, assigned_j, assigned_align,
                                                  gt_max, out);
}

// Round 3
// 230.248 us; speedup vs baseline: 1.5944x; 1.0646x over previous
//
#include <hip/hip_runtime.h>
#include <math.h>

#define BS   32
#define NA   8400
#define NMAX 64
#define NC   80
#define TOPKN 13
#define ICAP 1024   // in-gt candidate cap; physical max ~336+tail (gt wh <= 128 on 640^2)
#define PCAP 512    // positive (align>0) cap; subset of in-gt

// out layout (floats)
#define OFF_LABELS 0
#define OFF_BBOX   (BS*NA)                 // 268800
#define OFF_SCORES (BS*NA + BS*NA*4)       // 1344000
#define OFF_FG     (BS*NA*5 + BS*NA*NC)    // 22848000
#define OFF_TGT    (BS*NA*6 + BS*NA*NC)    // 23116800

__device__ __forceinline__ float ciou_f(float g0, float g1, float g2, float g3,
                                        float p0, float p1, float p2, float p3) {
    const float eps = 1e-7f;
    float w1 = g2 - g0, h1 = g3 - g1;
    float w2 = p2 - p0, h2 = p3 - p1;
    float iw = fmaxf(fminf(g2, p2) - fmaxf(g0, p0), 0.f);
    float ih = fmaxf(fminf(g3, p3) - fmaxf(g1, p1), 0.f);
    float inter = iw * ih;
    float uni = w1 * h1 + w2 * h2 - inter + eps;
    float iou = inter / uni;
    float cw = fmaxf(g2, p2) - fminf(g0, p0);
    float ch = fmaxf(g3, p3) - fminf(g1, p1);
    float c2 = cw * cw + ch * ch + eps;
    float dx = p0 + p2 - g0 - g2;
    float dy = p1 + p3 - g1 - g3;
    float rho2 = (dx * dx + dy * dy) * 0.25f;
    const float four_over_pi2 = 4.0f / 9.869604401089358f;
    float dv = atanf(w2 / h2) - atanf(w1 / h1);
    float v = four_over_pi2 * dv * dv;
    float a = v / (v - iou + (1.0f + eps));
    return iou - (rho2 / c2 + v * a);
}

__device__ __forceinline__ float pow6f(float x) { float x2 = x * x; return x2 * x2 * x2; }

// ONE code path for align so all recomputations are bit-identical.
__device__ __forceinline__ float align_at(int a, float g0, float g1, float g2, float g3,
                                          int label, const float* __restrict__ anc,
                                          const float* __restrict__ pb,
                                          const float* __restrict__ ps, float& d_out) {
    float ax = anc[a * 2 + 0], ay = anc[a * 2 + 1];
    float d = fminf(fminf(ax - g0, ay - g1), fminf(g2 - ax, g3 - ay));
    d_out = d;
    float al = 0.f;
    if (d > 1e-9f) {
        float p0 = pb[a * 4 + 0], p1 = pb[a * 4 + 1];
        float p2 = pb[a * 4 + 2], p3 = pb[a * 4 + 3];
        float cv = fmaxf(ciou_f(g0, g1, g2, g3, p0, p1, p2, p3), 0.f);
        if (cv > 0.f) al = ps[a * NC + label] * pow6f(cv);
    }
    return al;
}

// Phase A per (b,j):
//   pass1: d-only scan, compact in-gt anchors (kills atan divergence)
//   pass2: dense CIoU over compacted list -> positives list
//   top-K1 argmax passes (value desc, index asc) over positives
//   zero-tail: lowest-index zero entries fill remaining picks (claim iff in-gt)
__global__ __launch_bounds__(256) void kernA(const float* __restrict__ pd_scores,
                                             const float* __restrict__ pd_bboxes,
                                             const float* __restrict__ anc,
                                             const int*   __restrict__ gt_labels,
                                             const float* __restrict__ gt_bboxes,
                                             const float* __restrict__ mask_gt,
                                             int* __restrict__ claim_count,
                                             int* __restrict__ claimed_j) {
    const int j = blockIdx.x, b = blockIdx.y;
    const int tid = threadIdx.x;
    const int wid = tid >> 6, lane = tid & 63;

    __shared__ int   s_in[ICAP];
    __shared__ float s_pv[PCAP];
    __shared__ int   s_pi[PCAP];
    __shared__ int   s_icnt, s_pcnt;
    __shared__ float s_rv[4];
    __shared__ int   s_ri[4];
    __shared__ int   s_sel[TOPKN];

    if (mask_gt[b * NMAX + j] == 0.f) return;  // block-uniform exit

    if (tid == 0) { s_icnt = 0; s_pcnt = 0; }
    __syncthreads();

    const int   label = gt_labels[b * NMAX + j];
    const float g0 = gt_bboxes[(b * NMAX + j) * 4 + 0];
    const float g1 = gt_bboxes[(b * NMAX + j) * 4 + 1];
    const float g2 = gt_bboxes[(b * NMAX + j) * 4 + 2];
    const float g3 = gt_bboxes[(b * NMAX + j) * 4 + 3];
    const float* pb = pd_bboxes + (size_t)b * NA * 4;
    const float* ps = pd_scores + (size_t)b * NA * NC;
    const float2* anc2 = (const float2*)anc;

    // pass 1: cheap in-gt test only
    for (int a = tid; a < NA; a += 256) {
        float2 A = anc2[a];
        float d = fminf(fminf(A.x - g0, A.y - g1), fminf(g2 - A.x, g3 - A.y));
        if (d > 1e-9f) {
            int s = atomicAdd(&s_icnt, 1);
            if (s < ICAP) s_in[s] = a;
        }
    }
    __syncthreads();
    const int M = min(s_icnt, ICAP);

    // pass 2: dense CIoU over in-gt candidates
    for (int t = tid; t < M; t += 256) {
        int a = s_in[t];
        float p0 = pb[a * 4 + 0], p1 = pb[a * 4 + 1];
        float p2 = pb[a * 4 + 2], p3 = pb[a * 4 + 3];
        float cv = fmaxf(ciou_f(g0, g1, g2, g3, p0, p1, p2, p3), 0.f);
        if (cv > 0.f) {
            float al = ps[a * NC + label] * pow6f(cv);
            int s = atomicAdd(&s_pcnt, 1);
            if (s < PCAP) { s_pv[s] = al; s_pi[s] = a; }
        }
    }
    __syncthreads();
    const int P = min(s_pcnt, PCAP);
    const int K1 = min(P, TOPKN);

    for (int k = 0; k < K1; k++) {
        float bv = -2.f; int bi = NA;
        for (int t = tid; t < P; t += 256) {
            float v = s_pv[t];
            int   i = s_pi[t];
            if (v > bv || (v == bv && i < bi)) { bv = v; bi = i; }
        }
        #pragma unroll
        for (int off = 32; off >= 1; off >>= 1) {
            float v2 = __shfl_down(bv, off, 64);
            int   i2 = __shfl_down(bi, off, 64);
            if (v2 > bv || (v2 == bv && i2 < bi)) { bv = v2; bi = i2; }
        }
        if (lane == 0) { s_rv[wid] = bv; s_ri[wid] = bi; }
        __syncthreads();
        if (tid == 0) {
            float fv = s_rv[0]; int fi = s_ri[0];
            #pragma unroll
            for (int w = 1; w < 4; w++) {
                float v2 = s_rv[w]; int i2 = s_ri[w];
                if (v2 > fv || (v2 == fv && i2 < fi)) { fv = v2; fi = i2; }
            }
            s_sel[k] = fi;
            for (int t = 0; t < P; t++) {
                if (s_pi[t] == fi) { s_pv[t] = -1.f; break; }
            }
        }
        __syncthreads();
    }

    // claims for selected positives (al>0 implies in-gt)
    if (tid < K1) {
        int a = s_sel[tid];
        atomicAdd(&claim_count[b * NA + a], 1);
        claimed_j[b * NA + a] = j;  // races only when count>1, where it's unused
    }

    // zero-tail: top_k fills remaining picks with lowest-index zero entries
    if (tid == 0 && K1 < TOPKN) {
        int need = TOPKN - K1;
        for (int a = 0; a < NA && need > 0; a++) {
            float d;
            float al = align_at(a, g0, g1, g2, g3, label, anc, pb, ps, d);
            if (al == 0.f) {
                if (d > 1e-9f) {
                    atomicAdd(&claim_count[b * NA + a], 1);
                    claimed_j[b * NA + a] = j;
                }
                need--;
            }
        }
    }
}

// Phase B (fused with old C1): resolve assignment, per-gt max, scalar outputs, fg list.
__global__ __launch_bounds__(256) void kernB(const float* __restrict__ pd_scores,
                                             const float* __restrict__ pd_bboxes,
                                             const float* __restrict__ anc,
                                             const int*   __restrict__ gt_labels,
                                             const float* __restrict__ gt_bboxes,
                                             const float* __restrict__ mask_gt,
                                             const int* __restrict__ claim_count,
                                             const int* __restrict__ claimed_j,
                                             int* __restrict__ assigned_j,
                                             float* __restrict__ assigned_align,
                                             unsigned int* __restrict__ gt_max,
                                             int* __restrict__ fg_cnt,
                                             int* __restrict__ fg_list,
                                             float* __restrict__ out) {
    int idx = blockIdx.x * blockDim.x + threadIdx.x;
    if (idx >= BS * NA) return;
    int b = idx / NA, a = idx - b * NA;

    int cnt = claim_count[idx];
    int ja = -1;

    if (cnt > 0) {
        float ax = anc[a * 2 + 0], ay = anc[a * 2 + 1];
        float p0 = pd_bboxes[((size_t)b * NA + a) * 4 + 0];
        float p1 = pd_bboxes[((size_t)b * NA + a) * 4 + 1];
        float p2 = pd_bboxes[((size_t)b * NA + a) * 4 + 2];
        float p3 = pd_bboxes[((size_t)b * NA + a) * 4 + 3];

        if (cnt == 1) {
            ja = claimed_j[idx];
        } else {
            // argmax_j overlaps (first max), overlaps = m ? clip0(ciou) : 0
            float best = -1.f; ja = 0;
            for (int j = 0; j < NMAX; j++) {
                float mgj = mask_gt[b * NMAX + j];
                float ov = 0.f;
                if (mgj != 0.f) {
                    float g0 = gt_bboxes[(b * NMAX + j) * 4 + 0];
                    float g1 = gt_bboxes[(b * NMAX + j) * 4 + 1];
                    float g2 = gt_bboxes[(b * NMAX + j) * 4 + 2];
                    float g3 = gt_bboxes[(b * NMAX + j) * 4 + 3];
                    float d = fminf(fminf(ax - g0, ay - g1), fminf(g2 - ax, g3 - ay));
                    if (d > 1e-9f)
                        ov = fmaxf(ciou_f(g0, g1, g2, g3, p0, p1, p2, p3), 0.f);
                }
                if (ov > best) { best = ov; ja = j; }
            }
        }

        // align_metric at (ja, a) with mask applied
        float val = 0.f;
        float mgj = mask_gt[b * NMAX + ja];
        if (mgj != 0.f) {
            float g0 = gt_bboxes[(b * NMAX + ja) * 4 + 0];
            float g1 = gt_bboxes[(b * NMAX + ja) * 4 + 1];
            float g2 = gt_bboxes[(b * NMAX + ja) * 4 + 2];
            float g3 = gt_bboxes[(b * NMAX + ja) * 4 + 3];
            float d = fminf(fminf(ax - g0, ay - g1), fminf(g2 - ax, g3 - ay));
            if (d > 1e-9f) {
                float cv = fmaxf(ciou_f(g0, g1, g2, g3, p0, p1, p2, p3), 0.f);
                if (cv > 0.f) {
                    int lab = gt_labels[b * NMAX + ja];
                    val = pd_scores[((size_t)b * NA + a) * NC + lab] * pow6f(cv);
                }
            }
        }
        assigned_j[idx] = ja;
        assigned_align[idx] = val;
        atomicMax(&gt_max[b * NMAX + ja], __float_as_uint(val));  // val>=0: uint order == float order
        int slot = atomicAdd(fg_cnt, 1);
        fg_list[slot] = idx;
    }

    // scalar outputs for ALL anchors (old C1)
    int fg = (cnt > 0);
    int tgt = fg ? ja : 0;
    out[OFF_LABELS + idx] = (float)gt_labels[b * NMAX + tgt];
    const float4 bb = *(const float4*)&gt_bboxes[(b * NMAX + tgt) * 4];
    *(float4*)&out[OFF_BBOX + idx * 4] = bb;
    out[OFF_FG + idx]  = fg ? 1.f : 0.f;
    out[OFF_TGT + idx] = (float)tgt;
}

// Phase D: scatter normalized scores for fg anchors only (scores region pre-zeroed).
__global__ __launch_bounds__(256) void kernD(const int* __restrict__ gt_labels,
                                             const int* __restrict__ assigned_j,
                                             const float* __restrict__ assigned_align,
                                             const unsigned int* __restrict__ gt_max,
                                             const int* __restrict__ fg_cnt,
                                             const int* __restrict__ fg_list,
                                             float* __restrict__ out) {
    int t = blockIdx.x * blockDim.x + threadIdx.x;
    if (t >= fg_cnt[0]) return;
    int idx = fg_list[t];
    int b = idx / NA;
    int ja = assigned_j[idx];
    float v = assigned_align[idx];
    float dyn = 0.4f * __uint_as_float(gt_max[b * NMAX + ja]);
    float sc = v / (dyn + 1e-9f);
    int lab = gt_labels[b * NMAX + ja];
    out[OFF_SCORES + (size_t)idx * NC + lab] = sc;
}

extern "C" void kernel_launch(void* const* d_in, const int* in_sizes, int n_in,
                              void* d_out, int out_size, void* d_ws, size_t ws_size,
                              hipStream_t stream) {
    const float* pd_scores = (const float*)d_in[0];
    const float* pd_bboxes = (const float*)d_in[1];
    const float* anc       = (const float*)d_in[2];
    const int*   gt_labels = (const int*)d_in[3];
    const float* gt_bboxes = (const float*)d_in[4];
    const float* mask_gt   = (const float*)d_in[5];
    float* out = (float*)d_out;

    char* ws = (char*)d_ws;
    // zero-init region (front): claim_count | gt_max | fg_cnt(+pad)
    size_t off = 0;
    int*          claim_count = (int*)(ws + off);          off += (size_t)BS * NA * 4;     // 1,075,200
    unsigned int* gt_max      = (unsigned int*)(ws + off); off += (size_t)BS * NMAX * 4;   // 8,192
    int*          fg_cnt      = (int*)(ws + off);          off += 16;
    const size_t zero_bytes = off;
    int*          claimed_j      = (int*)(ws + off);       off += (size_t)BS * NA * 4;
    int*          assigned_j     = (int*)(ws + off);       off += (size_t)BS * NA * 4;
    float*        assigned_align = (float*)(ws + off);     off += (size_t)BS * NA * 4;
    int*          fg_list        = (int*)(ws + off);       // BS*NMAX*TOPKN ints max

    hipMemsetAsync(d_ws, 0, zero_bytes, stream);
    hipMemsetAsync(out + OFF_SCORES, 0, (size_t)BS * NA * NC * 4, stream);  // 86 MB DMA fill

    kernA<<<dim3(NMAX, BS), 256, 0, stream>>>(pd_scores, pd_bboxes, anc, gt_labels,
                                              gt_bboxes, mask_gt, claim_count, claimed_j);
    int nanch = BS * NA;
    kernB<<<(nanch + 255) / 256, 256, 0, stream>>>(pd_scores, pd_bboxes, anc, gt_labels,
                                                   gt_bboxes, mask_gt, claim_count, claimed_j,
                                                   assigned_j, assigned_align, gt_max,
                                                   fg_cnt, fg_list, out);
    int maxfg = BS * NMAX * TOPKN;  // 26624 upper bound on claimed anchors
    kernD<<<(maxfg + 255) / 256, 256, 0, stream>>>(gt_labels, assigned_j, assigned_align,
                                                   gt_max, fg_cnt, fg_list, out);
}

// Round 4
// 196.429 us; speedup vs baseline: 1.8689x; 1.1722x over previous
//
#include <hip/hip_runtime.h>
#include <math.h>

#define BS   32
#define NA   8400
#define NMAX 64
#define NC   80
#define TOPKN 13
#define ICAP 1024   // in-gt candidate cap; physical max ~400 (gt wh <= 128 on 640^2)
#define PCAP 512    // positive (align>0) cap; subset of in-gt; 2 regs/thread @ 256 thr

// out layout (floats)
#define OFF_LABELS 0
#define OFF_BBOX   (BS*NA)                 // 268800
#define OFF_SCORES (BS*NA + BS*NA*4)       // 1344000
#define OFF_FG     (BS*NA*5 + BS*NA*NC)    // 22848000
#define OFF_TGT    (BS*NA*6 + BS*NA*NC)    // 23116800

__device__ __forceinline__ float ciou_f(float g0, float g1, float g2, float g3,
                                        float p0, float p1, float p2, float p3) {
    const float eps = 1e-7f;
    float w1 = g2 - g0, h1 = g3 - g1;
    float w2 = p2 - p0, h2 = p3 - p1;
    float iw = fmaxf(fminf(g2, p2) - fmaxf(g0, p0), 0.f);
    float ih = fmaxf(fminf(g3, p3) - fmaxf(g1, p1), 0.f);
    float inter = iw * ih;
    float uni = w1 * h1 + w2 * h2 - inter + eps;
    float iou = inter / uni;
    float cw = fmaxf(g2, p2) - fminf(g0, p0);
    float ch = fmaxf(g3, p3) - fminf(g1, p1);
    float c2 = cw * cw + ch * ch + eps;
    float dx = p0 + p2 - g0 - g2;
    float dy = p1 + p3 - g1 - g3;
    float rho2 = (dx * dx + dy * dy) * 0.25f;
    const float four_over_pi2 = 4.0f / 9.869604401089358f;
    float dv = atanf(w2 / h2) - atanf(w1 / h1);
    float v = four_over_pi2 * dv * dv;
    float a = v / (v - iou + (1.0f + eps));
    return iou - (rho2 / c2 + v * a);
}

__device__ __forceinline__ float pow6f(float x) { float x2 = x * x; return x2 * x2 * x2; }

// ONE code path for align so all recomputations are bit-identical.
__device__ __forceinline__ float align_at(int a, float g0, float g1, float g2, float g3,
                                          int label, const float* __restrict__ anc,
                                          const float* __restrict__ pb,
                                          const float* __restrict__ ps, float& d_out) {
    float ax = anc[a * 2 + 0], ay = anc[a * 2 + 1];
    float d = fminf(fminf(ax - g0, ay - g1), fminf(g2 - ax, g3 - ay));
    d_out = d;
    float al = 0.f;
    if (d > 1e-9f) {
        float p0 = pb[a * 4 + 0], p1 = pb[a * 4 + 1];
        float p2 = pb[a * 4 + 2], p3 = pb[a * 4 + 3];
        float cv = fmaxf(ciou_f(g0, g1, g2, g3, p0, p1, p2, p3), 0.f);
        if (cv > 0.f) al = ps[a * NC + label] * pow6f(cv);
    }
    return al;
}

// Phase A per (b,j):
//   tid0 zeroes gt_max[b,j] (replaces a ws memset; runs before kernB in stream order)
//   pass1: d-only scan, compact in-gt anchors (kills atan divergence)
//   pass2: dense CIoU -> positives (value,index) list
//   P<=13: claim all; else 13 register-resident argmax passes (value desc, index asc)
//   zero-tail: lowest-index zero entries fill remaining picks (claim iff in-gt)
__global__ __launch_bounds__(256) void kernA(const float* __restrict__ pd_scores,
                                             const float* __restrict__ pd_bboxes,
                                             const float* __restrict__ anc,
                                             const int*   __restrict__ gt_labels,
                                             const float* __restrict__ gt_bboxes,
                                             const float* __restrict__ mask_gt,
                                             int* __restrict__ claim_count,
                                             int* __restrict__ claimed_j,
                                             unsigned int* __restrict__ gt_max) {
    const int j = blockIdx.x, b = blockIdx.y;
    const int tid = threadIdx.x;
    const int wid = tid >> 6, lane = tid & 63;

    __shared__ int   s_in[ICAP];
    __shared__ float s_pv[PCAP];
    __shared__ int   s_pi[PCAP];
    __shared__ int   s_icnt, s_pcnt;
    __shared__ float s_rv[4];
    __shared__ int   s_ri[4];

    if (tid == 0) gt_max[b * NMAX + j] = 0u;   // zero-init before any kernB read

    if (mask_gt[b * NMAX + j] == 0.f) return;  // block-uniform exit

    if (tid == 0) { s_icnt = 0; s_pcnt = 0; }
    __syncthreads();

    const int   label = gt_labels[b * NMAX + j];
    const float g0 = gt_bboxes[(b * NMAX + j) * 4 + 0];
    const float g1 = gt_bboxes[(b * NMAX + j) * 4 + 1];
    const float g2 = gt_bboxes[(b * NMAX + j) * 4 + 2];
    const float g3 = gt_bboxes[(b * NMAX + j) * 4 + 3];
    const float* pb = pd_bboxes + (size_t)b * NA * 4;
    const float* ps = pd_scores + (size_t)b * NA * NC;
    const float2* anc2 = (const float2*)anc;

    // pass 1: cheap in-gt test only
    for (int a = tid; a < NA; a += 256) {
        float2 A = anc2[a];
        float d = fminf(fminf(A.x - g0, A.y - g1), fminf(g2 - A.x, g3 - A.y));
        if (d > 1e-9f) {
            int s = atomicAdd(&s_icnt, 1);
            if (s < ICAP) s_in[s] = a;
        }
    }
    __syncthreads();
    const int M = min(s_icnt, ICAP);

    // pass 2: dense CIoU over in-gt candidates
    for (int t = tid; t < M; t += 256) {
        int a = s_in[t];
        float p0 = pb[a * 4 + 0], p1 = pb[a * 4 + 1];
        float p2 = pb[a * 4 + 2], p3 = pb[a * 4 + 3];
        float cv = fmaxf(ciou_f(g0, g1, g2, g3, p0, p1, p2, p3), 0.f);
        if (cv > 0.f) {
            float al = ps[a * NC + label] * pow6f(cv);
            int s = atomicAdd(&s_pcnt, 1);
            if (s < PCAP) { s_pv[s] = al; s_pi[s] = a; }
        }
    }
    __syncthreads();
    const int P = min(s_pcnt, PCAP);
    int K1;

    if (P <= TOPKN) {
        // all positives selected by top_k; order irrelevant for claims
        K1 = P;
        if (tid < P) {
            int a = s_pi[tid];
            atomicAdd(&claim_count[b * NA + a], 1);
            claimed_j[b * NA + a] = j;
        }
    } else {
        K1 = TOPKN;
        // register-resident candidates: 2 per thread covers PCAP=512
        float v0 = -2.f, v1 = -2.f; int i0 = NA, i1 = NA;
        if (tid < P)       { v0 = s_pv[tid];       i0 = s_pi[tid]; }
        if (tid + 256 < P) { v1 = s_pv[tid + 256]; i1 = s_pi[tid + 256]; }
        for (int k = 0; k < TOPKN; k++) {
            float bv = v0; int bi = i0;
            if (v1 > bv || (v1 == bv && i1 < bi)) { bv = v1; bi = i1; }
            #pragma unroll
            for (int off = 32; off >= 1; off >>= 1) {
                float v2 = __shfl_down(bv, off, 64);
                int   i2 = __shfl_down(bi, off, 64);
                if (v2 > bv || (v2 == bv && i2 < bi)) { bv = v2; bi = i2; }
            }
            if (lane == 0) { s_rv[wid] = bv; s_ri[wid] = bi; }
            __syncthreads();
            float fv = s_rv[0]; int fi = s_ri[0];
            #pragma unroll
            for (int w = 1; w < 4; w++) {
                float v2 = s_rv[w]; int i2 = s_ri[w];
                if (v2 > fv || (v2 == fv && i2 < fi)) { fv = v2; fi = i2; }
            }
            if (i0 == fi) v0 = -1.f;   // winner self-clears (indices unique)
            if (i1 == fi) v1 = -1.f;
            if (tid == k) {
                atomicAdd(&claim_count[b * NA + fi], 1);
                claimed_j[b * NA + fi] = j;
            }
            __syncthreads();           // protect s_rv reuse next pass
        }
    }

    // zero-tail: top_k fills remaining picks with lowest-index zero entries;
    // zeros are ubiquitous (out-of-gt anchors) so this terminates in ~need steps.
    if (tid == 0 && K1 < TOPKN) {
        int need = TOPKN - K1;
        for (int a = 0; a < NA && need > 0; a++) {
            float d;
            float al = align_at(a, g0, g1, g2, g3, label, anc, pb, ps, d);
            if (al == 0.f) {
                if (d > 1e-9f) {
                    atomicAdd(&claim_count[b * NA + a], 1);
                    claimed_j[b * NA + a] = j;
                }
                need--;
            }
        }
    }
}

// Phase B: resolve assignment, per-gt max, scalar outputs; re-zero claim slots
// (claim_count lives inside the pre-zeroed scores output region).
__global__ __launch_bounds__(256) void kernB(const float* __restrict__ pd_scores,
                                             const float* __restrict__ pd_bboxes,
                                             const float* __restrict__ anc,
                                             const int*   __restrict__ gt_labels,
                                             const float* __restrict__ gt_bboxes,
                                             const float* __restrict__ mask_gt,
                                             int* __restrict__ claim_count,
                                             const int* __restrict__ claimed_j,
                                             int* __restrict__ assigned_j,
                                             float* __restrict__ assigned_align,
                                             unsigned int* __restrict__ gt_max,
                                             float* __restrict__ out) {
    int idx = blockIdx.x * blockDim.x + threadIdx.x;
    if (idx >= BS * NA) return;
    int b = idx / NA, a = idx - b * NA;

    int cnt = claim_count[idx];
    int ja = -1;

    if (cnt > 0) {
        claim_count[idx] = 0;  // restore scores-region zero before kernD scatters

        float ax = anc[a * 2 + 0], ay = anc[a * 2 + 1];
        float p0 = pd_bboxes[((size_t)b * NA + a) * 4 + 0];
        float p1 = pd_bboxes[((size_t)b * NA + a) * 4 + 1];
        float p2 = pd_bboxes[((size_t)b * NA + a) * 4 + 2];
        float p3 = pd_bboxes[((size_t)b * NA + a) * 4 + 3];

        if (cnt == 1) {
            ja = claimed_j[idx];
        } else {
            // argmax_j overlaps (first max), overlaps = m ? clip0(ciou) : 0
            float best = -1.f; ja = 0;
            for (int j = 0; j < NMAX; j++) {
                float mgj = mask_gt[b * NMAX + j];
                float ov = 0.f;
                if (mgj != 0.f) {
                    float g0 = gt_bboxes[(b * NMAX + j) * 4 + 0];
                    float g1 = gt_bboxes[(b * NMAX + j) * 4 + 1];
                    float g2 = gt_bboxes[(b * NMAX + j) * 4 + 2];
                    float g3 = gt_bboxes[(b * NMAX + j) * 4 + 3];
                    float d = fminf(fminf(ax - g0, ay - g1), fminf(g2 - ax, g3 - ay));
                    if (d > 1e-9f)
                        ov = fmaxf(ciou_f(g0, g1, g2, g3, p0, p1, p2, p3), 0.f);
                }
                if (ov > best) { best = ov; ja = j; }
            }
        }

        // align_metric at (ja, a) with mask applied
        float val = 0.f;
        float mgj = mask_gt[b * NMAX + ja];
        if (mgj != 0.f) {
            float g0 = gt_bboxes[(b * NMAX + ja) * 4 + 0];
            float g1 = gt_bboxes[(b * NMAX + ja) * 4 + 1];
            float g2 = gt_bboxes[(b * NMAX + ja) * 4 + 2];
            float g3 = gt_bboxes[(b * NMAX + ja) * 4 + 3];
            float d = fminf(fminf(ax - g0, ay - g1), fminf(g2 - ax, g3 - ay));
            if (d > 1e-9f) {
                float cv = fmaxf(ciou_f(g0, g1, g2, g3, p0, p1, p2, p3), 0.f);
                if (cv > 0.f) {
                    int lab = gt_labels[b * NMAX + ja];
                    val = pd_scores[((size_t)b * NA + a) * NC + lab] * pow6f(cv);
                }
            }
        }
        assigned_align[idx] = val;
        atomicMax(&gt_max[b * NMAX + ja], __float_as_uint(val));  // val>=0: uint order == float order
    }
    assigned_j[idx] = ja;  // -1 for unclaimed (kernD gate)

    // scalar outputs for ALL anchors
    int fg = (cnt > 0);
    int tgt = fg ? ja : 0;
    out[OFF_LABELS + idx] = (float)gt_labels[b * NMAX + tgt];
    const float4 bb = *(const float4*)&gt_bboxes[(b * NMAX + tgt) * 4];
    *(float4*)&out[OFF_BBOX + idx * 4] = bb;
    out[OFF_FG + idx]  = fg ? 1.f : 0.f;
    out[OFF_TGT + idx] = (float)tgt;
}

// Phase D: scatter normalized scores for fg anchors (scores region zero elsewhere).
__global__ __launch_bounds__(256) void kernD(const int* __restrict__ gt_labels,
                                             const int* __restrict__ assigned_j,
                                             const float* __restrict__ assigned_align,
                                             const unsigned int* __restrict__ gt_max,
                                             float* __restrict__ out) {
    int idx = blockIdx.x * blockDim.x + threadIdx.x;
    if (idx >= BS * NA) return;
    int ja = assigned_j[idx];
    if (ja < 0) return;
    int b = idx / NA;
    float v = assigned_align[idx];
    float dyn = 0.4f * __uint_as_float(gt_max[b * NMAX + ja]);
    float sc = v / (dyn + 1e-9f);
    int lab = gt_labels[b * NMAX + ja];
    out[OFF_SCORES + (size_t)idx * NC + lab] = sc;
}

extern "C" void kernel_launch(void* const* d_in, const int* in_sizes, int n_in,
                              void* d_out, int out_size, void* d_ws, size_t ws_size,
                              hipStream_t stream) {
    const float* pd_scores = (const float*)d_in[0];
    const float* pd_bboxes = (const float*)d_in[1];
    const float* anc       = (const float*)d_in[2];
    const int*   gt_labels = (const int*)d_in[3];
    const float* gt_bboxes = (const float*)d_in[4];
    const float* mask_gt   = (const float*)d_in[5];
    float* out = (float*)d_out;

    // claim_count aliases the first BS*NA dwords of the (pre-zeroed) scores
    // region; kernB restores the touched slots to 0 before kernD scatters.
    int* claim_count = (int*)(out + OFF_SCORES);

    char* ws = (char*)d_ws;
    size_t off = 0;
    int*          claimed_j      = (int*)(ws + off);       off += (size_t)BS * NA * 4;
    int*          assigned_j     = (int*)(ws + off);       off += (size_t)BS * NA * 4;
    float*        assigned_align = (float*)(ws + off);     off += (size_t)BS * NA * 4;
    unsigned int* gt_max         = (unsigned int*)(ws + off);  // zero-inited inside kernA

    // single fill: zeroes scores output AND claim_count (aliased) at DMA rate
    hipMemsetAsync(out + OFF_SCORES, 0, (size_t)BS * NA * NC * 4, stream);

    kernA<<<dim3(NMAX, BS), 256, 0, stream>>>(pd_scores, pd_bboxes, anc, gt_labels,
                                              gt_bboxes, mask_gt, claim_count, claimed_j,
                                              gt_max);
    int nanch = BS * NA;
    kernB<<<(nanch + 255) / 256, 256, 0, stream>>>(pd_scores, pd_bboxes, anc, gt_labels,
                                                   gt_bboxes, mask_gt, claim_count, claimed_j,
                                                   assigned_j, assigned_align, gt_max, out);
    kernD<<<(nanch + 255) / 256, 256, 0, stream>>>(gt_labels, assigned_j, assigned_align,
                                                   gt_max, out);
}

// Round 5
// 195.651 us; speedup vs baseline: 1.8764x; 1.0040x over previous
//
#include <hip/hip_runtime.h>
#include <math.h>

#define BS   32
#define NA   8400
#define NMAX 64
#define NC   80
#define TOPKN 13
#define ICAP 1024   // in-gt candidate cap; physical max ~400 (gt wh <= 128 on 640^2)
#define PCAP 512    // positive (align>0) cap; 2 regs/thread @ 256 thr

// out layout (floats)
#define OFF_LABELS 0
#define OFF_BBOX   (BS*NA)                 // 268800
#define OFF_SCORES (BS*NA + BS*NA*4)       // 1344000
#define OFF_FG     (BS*NA*5 + BS*NA*NC)    // 22848000
#define OFF_TGT    (BS*NA*6 + BS*NA*NC)    // 23116800

__device__ __forceinline__ float ciou_f(float g0, float g1, float g2, float g3,
                                        float p0, float p1, float p2, float p3) {
    const float eps = 1e-7f;
    float w1 = g2 - g0, h1 = g3 - g1;
    float w2 = p2 - p0, h2 = p3 - p1;
    float iw = fmaxf(fminf(g2, p2) - fmaxf(g0, p0), 0.f);
    float ih = fmaxf(fminf(g3, p3) - fmaxf(g1, p1), 0.f);
    float inter = iw * ih;
    float uni = w1 * h1 + w2 * h2 - inter + eps;
    float iou = inter / uni;
    float cw = fmaxf(g2, p2) - fminf(g0, p0);
    float ch = fmaxf(g3, p3) - fminf(g1, p1);
    float c2 = cw * cw + ch * ch + eps;
    float dx = p0 + p2 - g0 - g2;
    float dy = p1 + p3 - g1 - g3;
    float rho2 = (dx * dx + dy * dy) * 0.25f;
    const float four_over_pi2 = 4.0f / 9.869604401089358f;
    float dv = atanf(w2 / h2) - atanf(w1 / h1);
    float v = four_over_pi2 * dv * dv;
    float a = v / (v - iou + (1.0f + eps));
    return iou - (rho2 / c2 + v * a);
}

__device__ __forceinline__ float pow6f(float x) { float x2 = x * x; return x2 * x2 * x2; }

// ONE code path for align so all recomputations match.
__device__ __forceinline__ float align_at(int a, float g0, float g1, float g2, float g3,
                                          int label, const float* __restrict__ anc,
                                          const float* __restrict__ pb,
                                          const float* __restrict__ ps, float& d_out) {
    float ax = anc[a * 2 + 0], ay = anc[a * 2 + 1];
    float d = fminf(fminf(ax - g0, ay - g1), fminf(g2 - ax, g3 - ay));
    d_out = d;
    float al = 0.f;
    if (d > 1e-9f) {
        float p0 = pb[a * 4 + 0], p1 = pb[a * 4 + 1];
        float p2 = pb[a * 4 + 2], p3 = pb[a * 4 + 3];
        float cv = fmaxf(ciou_f(g0, g1, g2, g3, p0, p1, p2, p3), 0.f);
        if (cv > 0.f) al = ps[a * NC + label] * pow6f(cv);
    }
    return al;
}

// Phase A per (b,j):
//   tid0 zeroes gt_max[b,j]
//   pass1: d-only scan, compact in-gt anchors
//   pass2: dense CIoU -> positives (value,index)
//   P<=13: claim all; else 13 register-resident argmax passes (value desc, index asc)
//   zero-tail: PARALLEL rank of lowest-index zero entries over anchors [0,256)
__global__ __launch_bounds__(256) void kernA(const float* __restrict__ pd_scores,
                                             const float* __restrict__ pd_bboxes,
                                             const float* __restrict__ anc,
                                             const int*   __restrict__ gt_labels,
                                             const float* __restrict__ gt_bboxes,
                                             const float* __restrict__ mask_gt,
                                             int* __restrict__ claim_count,
                                             int* __restrict__ claimed_j,
                                             float* __restrict__ claimed_val,
                                             unsigned int* __restrict__ gt_max) {
    const int j = blockIdx.x, b = blockIdx.y;
    const int tid = threadIdx.x;
    const int wid = tid >> 6, lane = tid & 63;

    __shared__ int   s_in[ICAP];
    __shared__ float s_pv[PCAP];
    __shared__ int   s_pi[PCAP];
    __shared__ int   s_icnt, s_pcnt;
    __shared__ float s_rv[4];
    __shared__ int   s_ri[4];
    __shared__ int   s_wz[4];

    if (tid == 0) gt_max[b * NMAX + j] = 0u;   // zero-init before any kernB read

    if (mask_gt[b * NMAX + j] == 0.f) return;  // block-uniform exit

    if (tid == 0) { s_icnt = 0; s_pcnt = 0; }
    __syncthreads();

    const int   label = gt_labels[b * NMAX + j];
    const float g0 = gt_bboxes[(b * NMAX + j) * 4 + 0];
    const float g1 = gt_bboxes[(b * NMAX + j) * 4 + 1];
    const float g2 = gt_bboxes[(b * NMAX + j) * 4 + 2];
    const float g3 = gt_bboxes[(b * NMAX + j) * 4 + 3];
    const float* pb = pd_bboxes + (size_t)b * NA * 4;
    const float* ps = pd_scores + (size_t)b * NA * NC;
    const float2* anc2 = (const float2*)anc;

    // pass 1: cheap in-gt test only
    for (int a = tid; a < NA; a += 256) {
        float2 A = anc2[a];
        float d = fminf(fminf(A.x - g0, A.y - g1), fminf(g2 - A.x, g3 - A.y));
        if (d > 1e-9f) {
            int s = atomicAdd(&s_icnt, 1);
            if (s < ICAP) s_in[s] = a;
        }
    }
    __syncthreads();
    const int M = min(s_icnt, ICAP);

    // pass 2: dense CIoU over in-gt candidates
    for (int t = tid; t < M; t += 256) {
        int a = s_in[t];
        float p0 = pb[a * 4 + 0], p1 = pb[a * 4 + 1];
        float p2 = pb[a * 4 + 2], p3 = pb[a * 4 + 3];
        float cv = fmaxf(ciou_f(g0, g1, g2, g3, p0, p1, p2, p3), 0.f);
        if (cv > 0.f) {
            float al = ps[a * NC + label] * pow6f(cv);
            int s = atomicAdd(&s_pcnt, 1);
            if (s < PCAP) { s_pv[s] = al; s_pi[s] = a; }
        }
    }
    __syncthreads();
    const int P = min(s_pcnt, PCAP);
    int K1;

    if (P <= TOPKN) {
        K1 = P;
        if (tid < P) {
            int a = s_pi[tid];
            atomicAdd(&claim_count[b * NA + a], 1);
            claimed_j[b * NA + a] = j;          // unique-use when count==1
            claimed_val[b * NA + a] = s_pv[tid];
        }
    } else {
        K1 = TOPKN;
        // register-resident candidates: 2 per thread covers PCAP=512
        float v0 = -2.f, v1 = -2.f; int i0 = NA, i1 = NA;
        if (tid < P)       { v0 = s_pv[tid];       i0 = s_pi[tid]; }
        if (tid + 256 < P) { v1 = s_pv[tid + 256]; i1 = s_pi[tid + 256]; }
        for (int k = 0; k < TOPKN; k++) {
            float bv = v0; int bi = i0;
            if (v1 > bv || (v1 == bv && i1 < bi)) { bv = v1; bi = i1; }
            #pragma unroll
            for (int off = 32; off >= 1; off >>= 1) {
                float v2 = __shfl_down(bv, off, 64);
                int   i2 = __shfl_down(bi, off, 64);
                if (v2 > bv || (v2 == bv && i2 < bi)) { bv = v2; bi = i2; }
            }
            if (lane == 0) { s_rv[wid] = bv; s_ri[wid] = bi; }
            __syncthreads();
            float fv = s_rv[0]; int fi = s_ri[0];
            #pragma unroll
            for (int w = 1; w < 4; w++) {
                float v2 = s_rv[w]; int i2 = s_ri[w];
                if (v2 > fv || (v2 == fv && i2 < fi)) { fv = v2; fi = i2; }
            }
            if (i0 == fi) v0 = -1.f;   // winner self-clears (indices unique)
            if (i1 == fi) v1 = -1.f;
            if (tid == k) {
                atomicAdd(&claim_count[b * NA + fi], 1);
                claimed_j[b * NA + fi] = j;
                claimed_val[b * NA + fi] = fv;
            }
            __syncthreads();           // protect s_rv reuse next pass
        }
    }

    // zero-tail: top_k fills remaining picks with the lowest-index zero entries;
    // parallel rank over anchors [0,256) (zeros ubiquitous -> nearly always enough).
    if (K1 < TOPKN) {
        const int need = TOPKN - K1;
        float d;
        float al = align_at(tid, g0, g1, g2, g3, label, anc, pb, ps, d);
        bool z = (al == 0.f);
        unsigned long long m = __ballot(z);
        int lanerank = __popcll(m & ((1ull << lane) - 1ull));
        if (lane == 0) s_wz[wid] = __popcll(m);
        __syncthreads();
        int base = 0, nz = 0;
        #pragma unroll
        for (int w = 0; w < 4; w++) { if (w < wid) base += s_wz[w]; nz += s_wz[w]; }
        int rank = base + lanerank;
        if (z && rank < need && d > 1e-9f) {
            atomicAdd(&claim_count[b * NA + tid], 1);
            claimed_j[b * NA + tid] = j;
            claimed_val[b * NA + tid] = 0.f;
        }
        // fallback (practically unreachable): fewer than `need` zeros in [0,256)
        if (tid == 0 && nz < need) {
            int rem = need - nz;
            for (int a = 256; a < NA && rem > 0; a++) {
                float dd;
                float a2 = align_at(a, g0, g1, g2, g3, label, anc, pb, ps, dd);
                if (a2 == 0.f) {
                    if (dd > 1e-9f) {
                        atomicAdd(&claim_count[b * NA + a], 1);
                        claimed_j[b * NA + a] = j;
                        claimed_val[b * NA + a] = 0.f;
                    }
                    rem--;
                }
            }
        }
    }
}

// Phase B: resolve assignment, per-gt max, scalar outputs; re-zero claim slots
// (claim_count lives inside the pre-zeroed scores output region).
__global__ __launch_bounds__(256) void kernB(const float* __restrict__ pd_scores,
                                             const float* __restrict__ pd_bboxes,
                                             const float* __restrict__ anc,
                                             const int*   __restrict__ gt_labels,
                                             const float* __restrict__ gt_bboxes,
                                             const float* __restrict__ mask_gt,
                                             int* __restrict__ claim_count,
                                             const int* __restrict__ claimed_j,
                                             const float* __restrict__ claimed_val,
                                             int* __restrict__ assigned_j,
                                             float* __restrict__ assigned_align,
                                             unsigned int* __restrict__ gt_max,
                                             float* __restrict__ out) {
    int idx = blockIdx.x * blockDim.x + threadIdx.x;
    if (idx >= BS * NA) return;
    int b = idx / NA, a = idx - b * NA;

    int cnt = claim_count[idx];
    int ja = -1;

    if (cnt > 0) {
        claim_count[idx] = 0;  // restore scores-region zero before kernD scatters

        float val;
        if (cnt == 1) {
            ja  = claimed_j[idx];
            val = claimed_val[idx];   // unique writer when cnt==1
        } else {
            float ax = anc[a * 2 + 0], ay = anc[a * 2 + 1];
            float p0 = pd_bboxes[((size_t)b * NA + a) * 4 + 0];
            float p1 = pd_bboxes[((size_t)b * NA + a) * 4 + 1];
            float p2 = pd_bboxes[((size_t)b * NA + a) * 4 + 2];
            float p3 = pd_bboxes[((size_t)b * NA + a) * 4 + 3];
            // argmax_j overlaps (first max), overlaps = m ? clip0(ciou) : 0
            float best = -1.f; ja = 0;
            for (int j = 0; j < NMAX; j++) {
                float mgj = mask_gt[b * NMAX + j];
                float ov = 0.f;
                if (mgj != 0.f) {
                    float g0 = gt_bboxes[(b * NMAX + j) * 4 + 0];
                    float g1 = gt_bboxes[(b * NMAX + j) * 4 + 1];
                    float g2 = gt_bboxes[(b * NMAX + j) * 4 + 2];
                    float g3 = gt_bboxes[(b * NMAX + j) * 4 + 3];
                    float d = fminf(fminf(ax - g0, ay - g1), fminf(g2 - ax, g3 - ay));
                    if (d > 1e-9f)
                        ov = fmaxf(ciou_f(g0, g1, g2, g3, p0, p1, p2, p3), 0.f);
                }
                if (ov > best) { best = ov; ja = j; }
            }
            // align_metric at (ja, a) with mask applied
            val = 0.f;
            float mgj = mask_gt[b * NMAX + ja];
            if (mgj != 0.f) {
                float g0 = gt_bboxes[(b * NMAX + ja) * 4 + 0];
                float g1 = gt_bboxes[(b * NMAX + ja) * 4 + 1];
                float g2 = gt_bboxes[(b * NMAX + ja) * 4 + 2];
                float g3 = gt_bboxes[(b * NMAX + ja) * 4 + 3];
                float d = fminf(fminf(ax - g0, ay - g1), fminf(g2 - ax, g3 - ay));
                if (d > 1e-9f) {
                    float cv = fmaxf(ciou_f(g0, g1, g2, g3, p0, p1, p2, p3), 0.f);
                    if (cv > 0.f) {
                        int lab = gt_labels[b * NMAX + ja];
                        val = pd_scores[((size_t)b * NA + a) * NC + lab] * pow6f(cv);
                    }
                }
            }
        }
        assigned_align[idx] = val;
        atomicMax(&gt_max[b * NMAX + ja], __float_as_uint(val));  // val>=0: uint order == float order
    }
    assigned_j[idx] = ja;  // -1 for unclaimed (kernD gate)

    // scalar outputs for ALL anchors
    int fg = (cnt > 0);
    int tgt = fg ? ja : 0;
    out[OFF_LABELS + idx] = (float)gt_labels[b * NMAX + tgt];
    const float4 bb = *(const float4*)&gt_bboxes[(b * NMAX + tgt) * 4];
    *(float4*)&out[OFF_BBOX + idx * 4] = bb;
    out[OFF_FG + idx]  = fg ? 1.f : 0.f;
    out[OFF_TGT + idx] = (float)tgt;
}

// Phase D: scatter normalized scores for fg anchors (scores region zero elsewhere).
__global__ __launch_bounds__(256) void kernD(const int* __restrict__ gt_labels,
                                             const int* __restrict__ assigned_j,
                                             const float* __restrict__ assigned_align,
                                             const unsigned int* __restrict__ gt_max,
                                             float* __restrict__ out) {
    int idx = blockIdx.x * blockDim.x + threadIdx.x;
    if (idx >= BS * NA) return;
    int ja = assigned_j[idx];
    if (ja < 0) return;
    int b = idx / NA;
    float v = assigned_align[idx];
    float dyn = 0.4f * __uint_as_float(gt_max[b * NMAX + ja]);
    float sc = v / (dyn + 1e-9f);
    int lab = gt_labels[b * NMAX + ja];
    out[OFF_SCORES + (size_t)idx * NC + lab] = sc;
}

extern "C" void kernel_launch(void* const* d_in, const int* in_sizes, int n_in,
                              void* d_out, int out_size, void* d_ws, size_t ws_size,
                              hipStream_t stream) {
    const float* pd_scores = (const float*)d_in[0];
    const float* pd_bboxes = (const float*)d_in[1];
    const float* anc       = (const float*)d_in[2];
    const int*   gt_labels = (const int*)d_in[3];
    const float* gt_bboxes = (const float*)d_in[4];
    const float* mask_gt   = (const float*)d_in[5];
    float* out = (float*)d_out;

    // claim_count aliases the first BS*NA dwords of the (pre-zeroed) scores
    // region; kernB restores the touched slots to 0 before kernD scatters.
    int* claim_count = (int*)(out + OFF_SCORES);

    char* ws = (char*)d_ws;
    size_t off = 0;
    int*          claimed_j      = (int*)(ws + off);       off += (size_t)BS * NA * 4;
    float*        claimed_val    = (float*)(ws + off);     off += (size_t)BS * NA * 4;
    int*          assigned_j     = (int*)(ws + off);       off += (size_t)BS * NA * 4;
    float*        assigned_align = (float*)(ws + off);     off += (size_t)BS * NA * 4;
    unsigned int* gt_max         = (unsigned int*)(ws + off);  // zero-inited inside kernA

    // single fill: zeroes scores output AND claim_count (aliased) at DMA rate
    hipMemsetAsync(out + OFF_SCORES, 0, (size_t)BS * NA * NC * 4, stream);

    kernA<<<dim3(NMAX, BS), 256, 0, stream>>>(pd_scores, pd_bboxes, anc, gt_labels,
                                              gt_bboxes, mask_gt, claim_count, claimed_j,
                                              claimed_val, gt_max);
    int nanch = BS * NA;
    kernB<<<(nanch + 255) / 256, 256, 0, stream>>>(pd_scores, pd_bboxes, anc, gt_labels,
                                                   gt_bboxes, mask_gt, claim_count, claimed_j,
                                                   claimed_val, assigned_j, assigned_align,
                                                   gt_max, out);
    kernD<<<(nanch + 255) / 256, 256, 0, stream>>>(gt_labels, assigned_j, assigned_align,
                                                   gt_max, out);
}